// Round 16
// baseline (29883.588 us; speedup 1.0000x reference)
//
#include <hip/hip_runtime.h>
#include <hip/hip_bf16.h>

#define B_   64
#define T_   2048
#define F_   256
#define H_   512

typedef __attribute__((ext_vector_type(8))) short bfrag;   // 8 bf16 (MFMA A/B)
typedef __attribute__((ext_vector_type(4))) int   int4v;
typedef __attribute__((ext_vector_type(4))) float f32x4;
typedef __attribute__((ext_vector_type(4))) float float4_t;

__device__ __forceinline__ float fsig(float x)  { return 1.0f / (1.0f + __expf(-x)); }
__device__ __forceinline__ float ftanh(float x) { return 2.0f / (1.0f + __expf(-2.0f * x)) - 1.0f; }
__device__ __forceinline__ unsigned short f2bfu(float f) {
  __hip_bfloat16 h = __float2bfloat16(f);
  return __builtin_bit_cast(unsigned short, h);
}

// ---------- one-time prep: weights fp32 -> bf16 in ws; combined gate bias ----
__global__ void prep_w(const float* __restrict__ Whh, const float* __restrict__ Wih,
                       const float* __restrict__ Wlin,
                       const float* __restrict__ bih, const float* __restrict__ bhh,
                       unsigned short* __restrict__ whh, unsigned short* __restrict__ wih,
                       unsigned short* __restrict__ wlin, float* __restrict__ bias_g) {
  const int idx = blockIdx.x * 256 + threadIdx.x;          // 65536 threads
  for (int i = idx; i < 4 * H_ * H_; i += 65536) whh[i] = f2bfu(Whh[i]);
  for (int i = idx; i < 4 * H_ * F_; i += 65536) wih[i] = f2bfu(Wih[i]);
  for (int i = idx; i < F_ * H_;     i += 65536) wlin[i] = f2bfu(Wlin[i]);
  if (idx < 4 * H_) bias_g[idx] = bih[idx] + bhh[idx];
}

// ---------- one-time prep: h0 = bf16(z), c = 0 ----------
__global__ void prep_h(const float* __restrict__ z, unsigned short* __restrict__ hb0,
                       float* __restrict__ cst) {
  const int i = blockIdx.x * 256 + threadIdx.x;            // 16384 threads
  for (int j = i; j < B_ * H_; j += 16384) { hb0[j] = f2bfu(z[j]); cst[j] = 0.f; }
}

// ---------- per-timestep kernel (one graph node per t) ----------
// Coherence across steps = kernel boundary (plain cached loads/stores only).
// WG 0..31 (gates): h-cols [16k,16k+16); wave q = gate; LDS gate-exchange.
// WG 32..39 (out):  out[t-1] cols [32j,32j+32) from h_t; skipped at t==0.
// MFMA layouts (m89-verified): A[m][k] m=lane&15, k=(lane>>4)*8+e;
// B[k][n] n=lane&15 (from row-major W[n][k]); D[m][n] n=lane&15, m=4*(lane>>4)+reg.
__global__ void __launch_bounds__(256, 1)
lstm_step(const float* __restrict__ x,
          const unsigned short* __restrict__ whh, const unsigned short* __restrict__ wih,
          const unsigned short* __restrict__ wlin,
          const float* __restrict__ bias_g, const float* __restrict__ blin,
          const unsigned short* __restrict__ hin, unsigned short* __restrict__ hout,
          float* __restrict__ cst, float* __restrict__ out, int t)
{
  __shared__ char smem[81920];   // [0,64K) h-tile [64][512]bf16 swz | [64K,80K) gate xchg

  const int wg  = blockIdx.x;
  const int tid = threadIdx.x;
  const int wv  = tid >> 6;
  const int l   = tid & 63;
  const int l16 = l & 15;
  const int qq  = l >> 4;
  const int lk  = qq << 3;
  const int m4  = qq << 2;

  if (wg >= 32 && t == 0) return;    // out path idle at t==0 (uniform per WG)

  // ---- stage h_t tile [64][512]bf16 -> LDS, swizzled (plain cached loads) ----
  #pragma unroll
  for (int i = 0; i < 16; ++i) {
    const int byte = (tid + 256 * i) * 16;
    const int row  = byte >> 10, off = byte & 1023;
    int4v v = *(const int4v*)((const char*)hin + byte);
    *(int4v*)(smem + row * 1024 + (off ^ ((row & 7) << 4))) = v;
  }
  __syncthreads();

  if (wg < 32) {
    const int k    = wg;                    // h-cols [16k, 16k+16)
    const int q    = wv;                    // this wave's gate
    const int grow = q * H_ + 16 * k + l16; // gate row (B-operand col)

    // ---- B-frags (bf16, cached; L2-warm across graph steps) ----
    int4v BH[16], BI[8];
    #pragma unroll
    for (int kt = 0; kt < 16; ++kt)
      BH[kt] = *(const int4v*)(whh + (size_t)grow * H_ + kt * 32 + lk);
    #pragma unroll
    for (int kt = 0; kt < 8; ++kt)
      BI[kt] = *(const int4v*)(wih + (size_t)grow * F_ + kt * 32 + lk);
    const float bsv = bias_g[grow];

    f32x4 acc[4] = {{bsv,bsv,bsv,bsv},{bsv,bsv,bsv,bsv},
                    {bsv,bsv,bsv,bsv},{bsv,bsv,bsv,bsv}};

    // ---- x part (K 0..255), fp32 -> bf16 on the fly ----
    #pragma unroll
    for (int mt = 0; mt < 4; ++mt) {
      const float* xr = x + ((size_t)(16 * mt + l16) * T_ + t) * F_ + lk;
      #pragma unroll
      for (int kt = 0; kt < 8; ++kt) {
        float4_t xa = *(const float4_t*)(xr + kt * 32);
        float4_t xb = *(const float4_t*)(xr + kt * 32 + 4);
        bfrag a;
        #pragma unroll
        for (int e = 0; e < 4; ++e) { a[e] = (short)f2bfu(xa[e]); a[4 + e] = (short)f2bfu(xb[e]); }
        acc[mt] = __builtin_amdgcn_mfma_f32_16x16x32_bf16(a, __builtin_bit_cast(bfrag, BI[kt]), acc[mt], 0, 0, 0);
      }
    }
    // ---- h part (K 256..767) from LDS ----
    #pragma unroll
    for (int mt = 0; mt < 4; ++mt) {
      const int row = 16 * mt + l16;
      #pragma unroll
      for (int kt = 0; kt < 16; ++kt) {
        bfrag a = *(const bfrag*)(smem + row * 1024 + ((kt * 64 + qq * 16) ^ ((row & 7) << 4)));
        acc[mt] = __builtin_amdgcn_mfma_f32_16x16x32_bf16(a, __builtin_bit_cast(bfrag, BH[kt]), acc[mt], 0, 0, 0);
      }
    }

    // ---- gate exchange: wave q writes its 4 m-tiles; wave wv reads 4 gates ----
    #pragma unroll
    for (int mt = 0; mt < 4; ++mt)
      *(f32x4*)(smem + 65536 + ((q * 4 + mt) * 64 + l) * 16) = acc[mt];
    __syncthreads();

    f32x4 gi = *(const f32x4*)(smem + 65536 + ((0 * 4 + wv) * 64 + l) * 16);
    f32x4 gf = *(const f32x4*)(smem + 65536 + ((1 * 4 + wv) * 64 + l) * 16);
    f32x4 gg = *(const f32x4*)(smem + 65536 + ((2 * 4 + wv) * 64 + l) * 16);
    f32x4 go = *(const f32x4*)(smem + 65536 + ((3 * 4 + wv) * 64 + l) * 16);

    #pragma unroll
    for (int r = 0; r < 4; ++r) {
      const int row = 16 * wv + m4 + r;
      const int col = 16 * k + l16;
      const int idx = row * H_ + col;
      float cv = cst[idx];
      float iv = fsig(gi[r]);
      float fv = fsig(gf[r]);
      float gv = ftanh(gg[r]);
      float ov = fsig(go[r]);
      float cn = fv * cv + iv * gv;
      cst[idx] = cn;
      hout[idx] = f2bfu(ov * ftanh(cn));
    }
  } else {
    // ---- out[t-1] = h_t @ W_lin^T + blin ----
    const int j   = wg - 32;
    const int oc0 = 32 * j;
    f32x4 oacc[2];
    #pragma unroll
    for (int nt = 0; nt < 2; ++nt) {
      float bv = blin[oc0 + nt * 16 + l16];
      oacc[nt] = (f32x4){bv, bv, bv, bv};
    }
    const int row = 16 * wv + l16;
    #pragma unroll
    for (int kt = 0; kt < 16; ++kt) {
      bfrag a = *(const bfrag*)(smem + row * 1024 + ((kt * 64 + qq * 16) ^ ((row & 7) << 4)));
      #pragma unroll
      for (int nt = 0; nt < 2; ++nt) {
        const int oc = oc0 + nt * 16 + l16;
        bfrag wl = __builtin_bit_cast(bfrag,
            *(const int4v*)(wlin + (size_t)oc * H_ + kt * 32 + lk));
        oacc[nt] = __builtin_amdgcn_mfma_f32_16x16x32_bf16(a, wl, oacc[nt], 0, 0, 0);
      }
    }
    #pragma unroll
    for (int nt = 0; nt < 2; ++nt)
      #pragma unroll
      for (int r = 0; r < 4; ++r)
        out[(size_t)(16 * wv + m4 + r) * T_ * F_ + (size_t)(t - 1) * F_ +
            oc0 + nt * 16 + l16] = oacc[nt][r];
  }
}

// ---------- tail: out[T-1] from h_T (direct global A-frags, no LDS) ----------
__global__ void __launch_bounds__(256, 1)
lstm_tail(const unsigned short* __restrict__ wlin, const float* __restrict__ blin,
          const unsigned short* __restrict__ hin, float* __restrict__ out)
{
  const int j   = blockIdx.x;          // 0..7, out cols [32j, +32)
  const int tid = threadIdx.x;
  const int wv  = tid >> 6;
  const int l   = tid & 63;
  const int l16 = l & 15;
  const int qq  = l >> 4;
  const int lk  = qq << 3;
  const int m4  = qq << 2;
  const int oc0 = 32 * j;

  f32x4 oacc[2];
  #pragma unroll
  for (int nt = 0; nt < 2; ++nt) {
    float bv = blin[oc0 + nt * 16 + l16];
    oacc[nt] = (f32x4){bv, bv, bv, bv};
  }
  const int row = 16 * wv + l16;
  #pragma unroll
  for (int kt = 0; kt < 16; ++kt) {
    bfrag a = __builtin_bit_cast(bfrag,
        *(const int4v*)(hin + (size_t)row * H_ + kt * 32 + lk));
    #pragma unroll
    for (int nt = 0; nt < 2; ++nt) {
      const int oc = oc0 + nt * 16 + l16;
      bfrag wl = __builtin_bit_cast(bfrag,
          *(const int4v*)(wlin + (size_t)oc * H_ + kt * 32 + lk));
      oacc[nt] = __builtin_amdgcn_mfma_f32_16x16x32_bf16(a, wl, oacc[nt], 0, 0, 0);
    }
  }
  #pragma unroll
  for (int nt = 0; nt < 2; ++nt)
    #pragma unroll
    for (int r = 0; r < 4; ++r)
      out[(size_t)(16 * wv + m4 + r) * T_ * F_ + (size_t)(T_ - 1) * F_ +
          oc0 + nt * 16 + l16] = oacc[nt][r];
}

extern "C" void kernel_launch(void* const* d_in, const int* in_sizes, int n_in,
                              void* d_out, int out_size, void* d_ws, size_t ws_size,
                              hipStream_t stream) {
  const float* z    = (const float*)d_in[0];
  const float* x    = (const float*)d_in[1];
  const float* Wih  = (const float*)d_in[2];
  const float* Whh  = (const float*)d_in[3];
  const float* bih  = (const float*)d_in[4];
  const float* bhh  = (const float*)d_in[5];
  const float* Wlin = (const float*)d_in[6];
  const float* blin = (const float*)d_in[7];
  float* out = (float*)d_out;

  char* w = (char*)d_ws;                               // ws layout (16B-aligned):
  unsigned short* whh_b  = (unsigned short*)(w);                    // 2 MB
  unsigned short* wih_b  = (unsigned short*)(w + (2u << 20));       // 1 MB
  unsigned short* wlin_b = (unsigned short*)(w + (3u << 20));       // 256 KB
  float*          bias_g = (float*)(w + (3u << 20) + (256u << 10)); // 8 KB
  unsigned short* hb0    = (unsigned short*)(w + (3472u << 10));    // 64 KB
  unsigned short* hb1    = (unsigned short*)(w + (3536u << 10));    // 64 KB
  float*          cst    = (float*)(w + (3600u << 10));             // 128 KB
  unsigned short* hb[2]  = {hb0, hb1};

  prep_w<<<256, 256, 0, stream>>>(Whh, Wih, Wlin, bih, bhh,
                                  whh_b, wih_b, wlin_b, bias_g);
  prep_h<<<64, 256, 0, stream>>>(z, hb0, cst);

  for (int t = 0; t < T_; ++t)
    lstm_step<<<40, 256, 0, stream>>>(x, whh_b, wih_b, wlin_b, bias_g, blin,
                                      hb[t & 1], hb[(t + 1) & 1], cst, out, t);
  lstm_tail<<<8, 256, 0, stream>>>(wlin_b, blin, hb[0], out);
}